// Round 8
// baseline (27.703 us; speedup 1.0000x reference)
//
#include <hip/hip_runtime.h>
#include <math.h>

#define ATOMS 200
#define W 4

static __device__ __forceinline__ float3 f3(float x, float y, float z) {
    return make_float3(x, y, z);
}
static __device__ __forceinline__ float3 sub3(float3 a, float3 b) {
    return f3(a.x - b.x, a.y - b.y, a.z - b.z);
}
static __device__ __forceinline__ float dot3(float3 a, float3 b) {
    return fmaf(a.x, b.x, fmaf(a.y, b.y, a.z * b.z));
}
static __device__ __forceinline__ float3 cross3(float3 a, float3 b) {
    return f3(fmaf(a.y, b.z, -a.z * b.y),
              fmaf(a.z, b.x, -a.x * b.z),
              fmaf(a.x, b.y, -a.y * b.x));
}
static __device__ __forceinline__ float3 neg3(float3 a) {
    return f3(-a.x, -a.y, -a.z);   // folds into consumer fma -src modifiers
}

// 16B store with only 4B alignment guarantee (gfx950 multi-dword stores
// require dword alignment only)
struct __attribute__((packed, aligned(4))) f4s { float a, b, c, d; };

// asin via A&S 4.4.45: abs err <= 6.8e-5 rad (threshold is 2e-2)
static __device__ __forceinline__ float asin_fast(float x) {
    float a = fminf(fabsf(x), 1.0f);
    float t = __builtin_amdgcn_sqrtf(1.0f - a);
    float p = fmaf(a, -0.0187293f, 0.0742610f);
    p = fmaf(a, p, -0.2121144f);
    p = fmaf(a, p, 1.5707288f);
    return copysignf(fmaf(-t, p, 1.5707963267948966f), x);
}

// C4(K) = sum_{k=1}^{K} ceil(k/4) = (q+1)(2q+r) for K = 4q+r
static __device__ __host__ __forceinline__ int C4(int K) {
    int q = K >> 2, r = K & 3;
    return (q + 1) * (2 * q + r);
}

struct St { float3 d1, d3, u1; float r1; };

static __device__ __forceinline__ float wr_term(
    float3 u0, float3 u1, float3 u3, float r0, float r1, float r3, float3 d2)
{
    const float d01 = dot3(u0, u1) * (r0 * r1);
    const float d13 = dot3(u1, u3) * (r1 * r3);
    const float d30 = dot3(u3, u0) * (r3 * r0);
    const float omega = asin_fast(d01) + asin_fast(d13)
                      + 1.5707963267948966f + asin_fast(d30);
    const float sv  = -dot3(u0, d2);
    const float sgn = (sv > 0.f) ? 1.f : ((sv < 0.f) ? -1.f : 0.f);
    return omega * sgn * 0.15915494309189535f;
}

static __device__ __forceinline__ float elem_full(
    float3 a0, float3 a1, float3 p2, float3 p3, St& st)
{
    const float3 d0 = sub3(p2, a0), d1 = sub3(p3, a0);
    const float3 d2 = sub3(p2, a1), d3 = sub3(p3, a1);
    const float3 u0 = cross3(d0, d1);
    const float3 u1 = cross3(d1, d3);
    const float3 u3 = cross3(d2, d0);
    const float r0 = __builtin_amdgcn_rsqf(dot3(u0, u0));
    const float r1 = __builtin_amdgcn_rsqf(dot3(u1, u1));
    const float r3 = __builtin_amdgcn_rsqf(dot3(u3, u3));
    st.d1 = d1; st.d3 = d3; st.u1 = u1; st.r1 = r1;
    return wr_term(u0, u1, u3, r0, r1, r3, d2);
}

// rolled: d0 <- d1_prev, d2 <- d3_prev, u3 <- -u1_prev, r3 <- r1_prev
static __device__ __forceinline__ float elem_roll(
    float3 a0, float3 a1, float3 p3, St& st)
{
    const float3 d0 = st.d1, d2 = st.d3;
    const float3 d1 = sub3(p3, a0), d3 = sub3(p3, a1);
    const float3 u0 = cross3(d0, d1);
    const float3 u1 = cross3(d1, d3);
    const float3 u3 = neg3(st.u1);
    const float r0 = __builtin_amdgcn_rsqf(dot3(u0, u0));
    const float r1 = __builtin_amdgcn_rsqf(dot3(u1, u1));
    const float r3 = st.r1;
    const float res = wr_term(u0, u1, u3, r0, r1, r3, d2);
    st.d1 = d1; st.d3 = d3; st.u1 = u1; st.r1 = r1;
    return res;
}

__global__ __launch_bounds__(256, 8)  // 8 blocks/CU = 32 waves/CU -> VGPR<=64
void writhe_kernel(
    const float* __restrict__ xyz,
    float*       __restrict__ out,
    int S, int m /* = A-3 */, int CH /* chunks per frame */)
{
    const int g = blockIdx.x * blockDim.x + threadIdx.x;
    if (g >= CH) return;
    const int f = blockIdx.y;

    // branchless row inversion: h = CH - g; K = min row-length with C4(K) >= h
    const int h = CH - g;                          // 1..CH
    int K = (int)(__builtin_amdgcn_sqrtf(fmaf(8.f, (float)h, 4.f)) - 2.f);
    K = max(1, min(K, m));
    K += (int)(K < m && C4(K) < h);
    K += (int)(K < m && C4(K) < h);
    K -= (int)(K > 1 && C4(K - 1) >= h);

    const int i    = m - K;                        // row (segment-1 start)
    const int c    = g - (CH - C4(K));             // chunk within row
    const int j0   = i + 2 + 4 * c;                // first j of this chunk
    const int nrem = min(W, K - 4 * c);            // valid elements (1..4)
    const int s0   = i * m - (i * (i - 1)) / 2 + 4 * c;

    // window offsets (clamped to row end)
    const int o2 = min(2, nrem), o3 = min(3, nrem), o4 = min(4, nrem);

    const float3* __restrict__ P =
        reinterpret_cast<const float3*>(xyz) + (size_t)f * ATOMS;

    const float3 a0 = P[i], a1 = P[i + 1];
    const float3 q0 = P[j0],      q1 = P[j0 + 1];
    const float3 q2 = P[j0 + o2], q3 = P[j0 + o3], q4 = P[j0 + o4];

    St st;
    const float r0v = elem_full(a0, a1, q0, q1, st);
    const float r1v = elem_roll(a0, a1, q2, st);
    const float r2v = elem_roll(a0, a1, q3, st);
    const float r3v = elem_roll(a0, a1, q4, st);

    float* o = out + (size_t)f * S + s0;
    if (nrem == W) {                 // 97% of threads: one 16B store
        f4s v; v.a = r0v; v.b = r1v; v.c = r2v; v.d = r3v;
        *reinterpret_cast<f4s*>(o) = v;
    } else {                         // row tail
        o[0] = r0v;
        if (nrem > 1) o[1] = r1v;
        if (nrem > 2) o[2] = r2v;
    }
}

extern "C" void kernel_launch(void* const* d_in, const int* in_sizes, int n_in,
                              void* d_out, int out_size, void* d_ws, size_t ws_size,
                              hipStream_t stream)
{
    const float* xyz = (const float*)d_in[0];
    float*       out = (float*)d_out;

    const int F = in_sizes[0] / (ATOMS * 3);
    const int S = out_size / F;              // = (A-2)(A-3)/2
    const int m = (int)((-1.0 + sqrt(1.0 + 8.0 * (double)S)) * 0.5 + 0.5);

    const int q = m >> 2, r = m & 3;
    const int CH = (q + 1) * (2 * q + r);    // chunks per frame

    dim3 grid((CH + 255) / 256, F);
    writhe_kernel<<<grid, 256, 0, stream>>>(xyz, out, S, m, CH);
}

// Round 9
// 25.464 us; speedup vs baseline: 1.0879x; 1.0879x over previous
//
#include <hip/hip_runtime.h>
#include <math.h>

#define ATOMS 200
#define W 4

static __device__ __forceinline__ float3 f3(float x, float y, float z) {
    return make_float3(x, y, z);
}
static __device__ __forceinline__ float3 sub3(float3 a, float3 b) {
    return f3(a.x - b.x, a.y - b.y, a.z - b.z);
}
static __device__ __forceinline__ float dot3(float3 a, float3 b) {
    return fmaf(a.x, b.x, fmaf(a.y, b.y, a.z * b.z));
}
static __device__ __forceinline__ float3 cross3(float3 a, float3 b) {
    return f3(fmaf(a.y, b.z, -a.z * b.y),
              fmaf(a.z, b.x, -a.x * b.z),
              fmaf(a.x, b.y, -a.y * b.x));
}
static __device__ __forceinline__ float3 neg3(float3 a) {
    return f3(-a.x, -a.y, -a.z);   // folds into consumer fma -src modifiers
}

// asin via A&S 4.4.45: abs err <= 6.8e-5 rad (threshold is 2e-2)
static __device__ __forceinline__ float asin_fast(float x) {
    float a = fminf(fabsf(x), 1.0f);
    float t = __builtin_amdgcn_sqrtf(1.0f - a);
    float p = fmaf(a, -0.0187293f, 0.0742610f);
    p = fmaf(a, p, -0.2121144f);
    p = fmaf(a, p, 1.5707288f);
    return copysignf(fmaf(-t, p, 1.5707963267948966f), x);
}

// C4(K) = sum_{k=1}^{K} ceil(k/4) = (q+1)(2q+r) for K = 4q+r
static __device__ __host__ __forceinline__ int C4(int K) {
    int q = K >> 2, r = K & 3;
    return (q + 1) * (2 * q + r);
}

struct St { float3 d1, d3, u1; float r1; };

static __device__ __forceinline__ float wr_term(
    float3 u0, float3 u1, float3 u3, float r0, float r1, float r3, float3 d2)
{
    const float d01 = dot3(u0, u1) * (r0 * r1);
    const float d13 = dot3(u1, u3) * (r1 * r3);
    const float d30 = dot3(u3, u0) * (r3 * r0);
    const float omega = asin_fast(d01) + asin_fast(d13)
                      + 1.5707963267948966f + asin_fast(d30);
    const float sv  = -dot3(u0, d2);
    const float sgn = (sv > 0.f) ? 1.f : ((sv < 0.f) ? -1.f : 0.f);
    return omega * sgn * 0.15915494309189535f;
}

static __device__ __forceinline__ float elem_full(
    float3 a0, float3 a1, float3 p2, float3 p3, St& st)
{
    const float3 d0 = sub3(p2, a0), d1 = sub3(p3, a0);
    const float3 d2 = sub3(p2, a1), d3 = sub3(p3, a1);
    const float3 u0 = cross3(d0, d1);
    const float3 u1 = cross3(d1, d3);
    const float3 u3 = cross3(d2, d0);
    const float r0 = __builtin_amdgcn_rsqf(dot3(u0, u0));
    const float r1 = __builtin_amdgcn_rsqf(dot3(u1, u1));
    const float r3 = __builtin_amdgcn_rsqf(dot3(u3, u3));
    st.d1 = d1; st.d3 = d3; st.u1 = u1; st.r1 = r1;
    return wr_term(u0, u1, u3, r0, r1, r3, d2);
}

// rolled: d0 <- d1_prev, d2 <- d3_prev, u3 <- -u1_prev, r3 <- r1_prev
static __device__ __forceinline__ float elem_roll(
    float3 a0, float3 a1, float3 p3, St& st)
{
    const float3 d0 = st.d1, d2 = st.d3;
    const float3 d1 = sub3(p3, a0), d3 = sub3(p3, a1);
    const float3 u0 = cross3(d0, d1);
    const float3 u1 = cross3(d1, d3);
    const float3 u3 = neg3(st.u1);
    const float r0 = __builtin_amdgcn_rsqf(dot3(u0, u0));
    const float r1 = __builtin_amdgcn_rsqf(dot3(u1, u1));
    const float r3 = st.r1;
    const float res = wr_term(u0, u1, u3, r0, r1, r3, d2);
    st.d1 = d1; st.d3 = d3; st.u1 = u1; st.r1 = r1;
    return res;
}

__global__ __launch_bounds__(256, 8)  // target: 8 waves/SIMD, VGPR <= 64
void writhe_kernel(
    const float* __restrict__ xyz,
    float*       __restrict__ out,
    int S, int m /* = A-3 */, int CH /* chunks per frame */)
{
    const int g = blockIdx.x * blockDim.x + threadIdx.x;
    if (g >= CH) return;
    const int f = blockIdx.y;

    // branchless row inversion: h = CH - g; K = min row-length with C4(K) >= h
    const int h = CH - g;                          // 1..CH
    int K = (int)(__builtin_amdgcn_sqrtf(fmaf(8.f, (float)h, 4.f)) - 2.f);
    K = max(1, min(K, m));
    K += (int)(K < m && C4(K) < h);
    K += (int)(K < m && C4(K) < h);
    K -= (int)(K > 1 && C4(K - 1) >= h);

    const int i    = m - K;                        // row (segment-1 start)
    const int c    = g - (CH - C4(K));             // chunk within row
    const int j0   = i + 2 + 4 * c;                // first j of this chunk
    const int nrem = min(W, K - 4 * c);            // valid elements (1..4)
    const int s0   = i * m - (i * (i - 1)) / 2 + 4 * c;

    const float3* __restrict__ P =
        reinterpret_cast<const float3*>(xyz) + (size_t)f * ATOMS;

    // Upfront loads. Clamp to ATOMS-1: the last needed atom of EVERY row is
    // exactly atom ATOMS-1 (i+K+2 == m+2 == ATOMS-1), so the clamp never
    // corrupts a valid element — only the masked-out tail garbage.
    const float3 a0 = P[i], a1 = P[i + 1];
    const float3 q0 = P[j0];
    const float3 q1 = P[j0 + 1];
    const float3 q2 = P[min(j0 + 2, ATOMS - 1)];
    const float3 q3 = P[min(j0 + 3, ATOMS - 1)];
    const float3 q4 = P[min(j0 + 4, ATOMS - 1)];

    // Serial element schedule, pinned with sched_barrier(0) so the compiler
    // does NOT interleave elements (interleaving inflates peak VGPR past 64
    // and spills under the launch-bounds cap — that was round 8's regression).
    St st;
    const float r0v = elem_full(a0, a1, q0, q1, st);
    __builtin_amdgcn_sched_barrier(0);
    const float r1v = elem_roll(a0, a1, q2, st);
    __builtin_amdgcn_sched_barrier(0);
    const float r2v = elem_roll(a0, a1, q3, st);
    __builtin_amdgcn_sched_barrier(0);
    const float r3v = elem_roll(a0, a1, q4, st);

    float* o = out + (size_t)f * S + s0;
    o[0] = r0v;
    if (nrem > 1) o[1] = r1v;
    if (nrem > 2) o[2] = r2v;
    if (nrem > 3) o[3] = r3v;
}

extern "C" void kernel_launch(void* const* d_in, const int* in_sizes, int n_in,
                              void* d_out, int out_size, void* d_ws, size_t ws_size,
                              hipStream_t stream)
{
    const float* xyz = (const float*)d_in[0];
    float*       out = (float*)d_out;

    const int F = in_sizes[0] / (ATOMS * 3);
    const int S = out_size / F;              // = (A-2)(A-3)/2
    const int m = (int)((-1.0 + sqrt(1.0 + 8.0 * (double)S)) * 0.5 + 0.5);

    const int q = m >> 2, r = m & 3;
    const int CH = (q + 1) * (2 * q + r);    // chunks per frame

    dim3 grid((CH + 255) / 256, F);
    writhe_kernel<<<grid, 256, 0, stream>>>(xyz, out, S, m, CH);
}

// Round 10
// 21.557 us; speedup vs baseline: 1.2851x; 1.1812x over previous
//
#include <hip/hip_runtime.h>
#include <math.h>

#define ATOMS 200
#define W 4
#define FB 2   // frames per thread (two independent dependency chains)

static __device__ __forceinline__ float3 f3(float x, float y, float z) {
    return make_float3(x, y, z);
}
static __device__ __forceinline__ float3 sub3(float3 a, float3 b) {
    return f3(a.x - b.x, a.y - b.y, a.z - b.z);
}
static __device__ __forceinline__ float dot3(float3 a, float3 b) {
    return fmaf(a.x, b.x, fmaf(a.y, b.y, a.z * b.z));
}
static __device__ __forceinline__ float3 cross3(float3 a, float3 b) {
    return f3(fmaf(a.y, b.z, -a.z * b.y),
              fmaf(a.z, b.x, -a.x * b.z),
              fmaf(a.x, b.y, -a.y * b.x));
}
static __device__ __forceinline__ float3 neg3(float3 a) {
    return f3(-a.x, -a.y, -a.z);   // folds into consumer fma -src modifiers
}

// 16B store with only 4B alignment guarantee (gfx950 multi-dword stores
// require dword alignment only)
struct __attribute__((packed, aligned(4))) f4s { float a, b, c, d; };

// asin via A&S 4.4.45: abs err <= 6.8e-5 rad (threshold is 2e-2)
static __device__ __forceinline__ float asin_fast(float x) {
    float a = fminf(fabsf(x), 1.0f);
    float t = __builtin_amdgcn_sqrtf(1.0f - a);
    float p = fmaf(a, -0.0187293f, 0.0742610f);
    p = fmaf(a, p, -0.2121144f);
    p = fmaf(a, p, 1.5707288f);
    return copysignf(fmaf(-t, p, 1.5707963267948966f), x);
}

// C4(K) = sum_{k=1}^{K} ceil(k/4) = (q+1)(2q+r) for K = 4q+r
static __device__ __host__ __forceinline__ int C4(int K) {
    int q = K >> 2, r = K & 3;
    return (q + 1) * (2 * q + r);
}

struct St { float3 d1, d3, u1; float r1; };

static __device__ __forceinline__ float wr_term(
    float3 u0, float3 u1, float3 u3, float r0, float r1, float r3, float3 d2)
{
    const float d01 = dot3(u0, u1) * (r0 * r1);
    const float d13 = dot3(u1, u3) * (r1 * r3);
    const float d30 = dot3(u3, u0) * (r3 * r0);
    const float omega = asin_fast(d01) + asin_fast(d13)
                      + 1.5707963267948966f + asin_fast(d30);
    const float sv  = -dot3(u0, d2);
    const float sgn = (sv > 0.f) ? 1.f : ((sv < 0.f) ? -1.f : 0.f);
    return omega * sgn * 0.15915494309189535f;
}

static __device__ __forceinline__ float elem_full(
    float3 a0, float3 a1, float3 p2, float3 p3, St& st)
{
    const float3 d0 = sub3(p2, a0), d1 = sub3(p3, a0);
    const float3 d2 = sub3(p2, a1), d3 = sub3(p3, a1);
    const float3 u0 = cross3(d0, d1);
    const float3 u1 = cross3(d1, d3);
    const float3 u3 = cross3(d2, d0);
    const float r0 = __builtin_amdgcn_rsqf(dot3(u0, u0));
    const float r1 = __builtin_amdgcn_rsqf(dot3(u1, u1));
    const float r3 = __builtin_amdgcn_rsqf(dot3(u3, u3));
    st.d1 = d1; st.d3 = d3; st.u1 = u1; st.r1 = r1;
    return wr_term(u0, u1, u3, r0, r1, r3, d2);
}

// rolled: d0 <- d1_prev, d2 <- d3_prev, u3 <- -u1_prev, r3 <- r1_prev
static __device__ __forceinline__ float elem_roll(
    float3 a0, float3 a1, float3 p3, St& st)
{
    const float3 d0 = st.d1, d2 = st.d3;
    const float3 d1 = sub3(p3, a0), d3 = sub3(p3, a1);
    const float3 u0 = cross3(d0, d1);
    const float3 u1 = cross3(d1, d3);
    const float3 u3 = neg3(st.u1);
    const float r0 = __builtin_amdgcn_rsqf(dot3(u0, u0));
    const float r1 = __builtin_amdgcn_rsqf(dot3(u1, u1));
    const float r3 = st.r1;
    const float res = wr_term(u0, u1, u3, r0, r1, r3, d2);
    st.d1 = d1; st.d3 = d3; st.u1 = u1; st.r1 = r1;
    return res;
}

// soft cap: 4 waves/EU -> VGPR <= 128. Natural pressure ~100-115 after
// dropping the prefetch window, so no spill (R8's 64-cap DID spill).
__global__ __launch_bounds__(256, 4)
void writhe_kernel(
    const float* __restrict__ xyz,
    float*       __restrict__ out,
    int S, int m /* = A-3 */, int CH /* chunks per frame */, int F)
{
    const int g = blockIdx.x * blockDim.x + threadIdx.x;
    if (g >= CH) return;
    const int f0 = blockIdx.y * FB;

    // branchless row inversion: h = CH - g; K = min row-length with C4(K) >= h
    const int h = CH - g;                          // 1..CH
    int K = (int)(__builtin_amdgcn_sqrtf(fmaf(8.f, (float)h, 4.f)) - 2.f);
    K = max(1, min(K, m));
    K += (int)(K < m && C4(K) < h);
    K += (int)(K < m && C4(K) < h);
    K -= (int)(K > 1 && C4(K - 1) >= h);

    const int i    = m - K;                        // row (segment-1 start)
    const int c    = g - (CH - C4(K));             // chunk within row
    const int j0   = i + 2 + 4 * c;                // first j of this chunk
    const int nrem = min(W, K - 4 * c);            // valid elements (1..4)
    const int s0   = i * m - (i * (i - 1)) / 2 + 4 * c;

    // window offsets (clamped to row end), shared across frames
    const int o2 = min(2, nrem), o3 = min(3, nrem), o4 = min(4, nrem);

    #pragma unroll
    for (int fb = 0; fb < FB; ++fb) {
        const int f = f0 + fb;
        if (f >= F) break;
        const float3* __restrict__ P =
            reinterpret_cast<const float3*>(xyz) + (size_t)f * ATOMS;

        // only the immediately-needed points are prefetched; the rolled
        // elements load their own p3 (L1-resident frame) to keep live
        // registers low -> 4 waves/SIMD instead of 2.
        const float3 a0 = P[i], a1 = P[i + 1];
        const float3 q0 = P[j0], q1 = P[j0 + 1];

        St st;
        const float r0v = elem_full(a0, a1, q0, q1, st);
        const float r1v = elem_roll(a0, a1, P[j0 + o2], st);
        const float r2v = elem_roll(a0, a1, P[j0 + o3], st);
        const float r3v = elem_roll(a0, a1, P[j0 + o4], st);

        float* o = out + (size_t)f * S + s0;
        if (nrem == W) {                 // 97% of threads: one 16B store
            f4s v; v.a = r0v; v.b = r1v; v.c = r2v; v.d = r3v;
            *reinterpret_cast<f4s*>(o) = v;
        } else {                         // row tail
            o[0] = r0v;
            if (nrem > 1) o[1] = r1v;
            if (nrem > 2) o[2] = r2v;
        }
    }
}

extern "C" void kernel_launch(void* const* d_in, const int* in_sizes, int n_in,
                              void* d_out, int out_size, void* d_ws, size_t ws_size,
                              hipStream_t stream)
{
    const float* xyz = (const float*)d_in[0];
    float*       out = (float*)d_out;

    const int F = in_sizes[0] / (ATOMS * 3);
    const int S = out_size / F;              // = (A-2)(A-3)/2
    const int m = (int)((-1.0 + sqrt(1.0 + 8.0 * (double)S)) * 0.5 + 0.5);

    const int q = m >> 2, r = m & 3;
    const int CH = (q + 1) * (2 * q + r);    // chunks per frame

    dim3 grid((CH + 255) / 256, (F + FB - 1) / FB);
    writhe_kernel<<<grid, 256, 0, stream>>>(xyz, out, S, m, CH, F);
}